// Round 3
// baseline (6154.686 us; speedup 1.0000x reference)
//
#include <hip/hip_runtime.h>
#include <math.h>

// Persistent fp16-MFMA LSTM, round 6. T=512, B=64, IN=512, H=1024, K=1536.
// 256 blocks x 256 threads (1 block/CU). Changes vs round 5:
//  - ALL-SCAN barrier: each block release-stores flags[blk]=t+1 (sc1) after
//    the __syncthreads vmcnt drain; every block's wave 0 scans all 256 flags
//    itself (2x u64 agent loads per lane = whole 1KB array per iteration).
//    No fetch_add (no same-line RMW serialization), no RMW-return stall, no
//    publish hop, no aggregator.
//  - acquire fence / buffer_inv DELETED. h (and fallback x) loads are back
//    to sc1 IF-direct; combx plain loads stay L2-resident across steps (no
//    more per-step invalidation storms).
//  - rest unchanged from round 5: out-stores + xpart(t+1) hidden in the wait
//    window, 4-chain h-MFMA, packed 8B h-stores, fast sigmoid/tanh.

namespace {

constexpr int T_STEPS = 512;
constexpr int B = 64;
constexpr int IN = 512;
constexpr int H = 1024;
constexpr int K = IN + H;    // 1536
constexpr int NBLK = 256;
constexpr int NXMF = IN / 32;  // 16 x-part MFMAs
constexpr int NHMF = H / 32;   // 32 h-part MFMAs
constexpr int WPITCH = K + 8;  // one-time staging pitch (halves)

// ws layout (bytes) — unchanged so NEED_PRE is identical.
constexpr size_t HBUF_OFF = 0;                                  // 2*B*H fp16
constexpr size_t XBUF_OFF = HBUF_OFF + 2ull * B * H * 2;        // 2*B*IN fp16
constexpr size_t BAR_OFF = XBUF_OFF + 2ull * B * IN * 2;        // 1056 uints
constexpr size_t COMBX_OFF = BAR_OFF + 1056ull * 4;             // T*B*IN fp16
constexpr size_t NEED_PRE = COMBX_OFF + (size_t)T_STEPS * B * IN * 2;

typedef __attribute__((ext_vector_type(8))) _Float16 f16x8;
typedef __attribute__((ext_vector_type(4))) float f32x4;

__device__ __forceinline__ f16x8 load_sc1_16B(const _Float16* p) {
  union {
    unsigned long long u[2];
    f16x8 v;
  } cv;
  const unsigned long long* q = (const unsigned long long*)p;
  cv.u[0] = __hip_atomic_load(q, __ATOMIC_RELAXED, __HIP_MEMORY_SCOPE_AGENT);
  cv.u[1] =
      __hip_atomic_load(q + 1, __ATOMIC_RELAXED, __HIP_MEMORY_SCOPE_AGENT);
  return cv.v;
}

__device__ __forceinline__ void store_sc1_u64(_Float16* p,
                                              unsigned long long v) {
  __hip_atomic_store((unsigned long long*)p, v, __ATOMIC_RELAXED,
                     __HIP_MEMORY_SCOPE_AGENT);
}

__device__ __forceinline__ void store_sc1_u32(unsigned* p, unsigned v) {
  __hip_atomic_store(p, v, __ATOMIC_RELAXED, __HIP_MEMORY_SCOPE_AGENT);
}

// |err| ~1e-7 relative — far below the fp16 h quantization already present.
__device__ __forceinline__ float fast_sigmoid(float z) {
  return __builtin_amdgcn_rcpf(1.0f + __expf(-z));
}
__device__ __forceinline__ float fast_tanh(float z) {
  return 1.0f - 2.0f * __builtin_amdgcn_rcpf(1.0f + __expf(2.0f * z));
}

// Prefilled-mode prep: combx[t][b][k] = fp16(x), zero hbuf, zero barrier.
__global__ void prep_pre(const float* __restrict__ x,
                         _Float16* __restrict__ combx,
                         _Float16* __restrict__ hbuf,
                         unsigned* __restrict__ bar) {
  const size_t i = (size_t)blockIdx.x * 256 + threadIdx.x;
  if (i < (size_t)T_STEPS * B * IN) combx[i] = (_Float16)x[i];
  if (i < 2ull * B * H) hbuf[i] = (_Float16)0.f;
  if (i < 1056) bar[i] = 0u;
}

// Fallback prep: xbuf[0] = fp16(x[0]), zero hbuf, zero barrier.
__global__ void prep_fb(const float* __restrict__ x,
                        _Float16* __restrict__ xbuf,
                        _Float16* __restrict__ hbuf,
                        unsigned* __restrict__ bar) {
  const size_t i = (size_t)blockIdx.x * 256 + threadIdx.x;
  if (i < (size_t)B * IN) xbuf[i] = (_Float16)x[i];
  if (i < 2ull * B * H) hbuf[i] = (_Float16)0.f;
  if (i < 1056) bar[i] = 0u;
}

template <bool PRE>
__global__ __launch_bounds__(256, 1) void lstm_persist(
    const float* __restrict__ x, const float* __restrict__ Wf,
    const float* __restrict__ Wi, const float* __restrict__ Wg,
    const float* __restrict__ Wo, const float* __restrict__ bf,
    const float* __restrict__ bi_, const float* __restrict__ bg,
    const float* __restrict__ bo, float* __restrict__ out,
    _Float16* __restrict__ combx, _Float16* __restrict__ xbuf,
    _Float16* __restrict__ hbuf, unsigned* __restrict__ bar) {
  __shared__ _Float16 Wlds[16 * WPITCH];  // one-time staging only

  const int blk = blockIdx.x;
  const int tid = threadIdx.x;
  const int j0 = blk * 4;

  // ---- one-time: stage W slice (coalesced), then lift B-frags to regs ----
  {
    const float* wptr[4] = {Wf, Wi, Wg, Wo};
#pragma unroll
    for (int g = 0; g < 4; ++g) {
      const float* wsrc = wptr[g];
      for (int it = 0; it < K / 256; ++it) {
        const int k = it * 256 + tid;
        const float4 w = *(const float4*)(wsrc + (size_t)k * H + j0);
        Wlds[(g * 4 + 0) * WPITCH + k] = (_Float16)w.x;
        Wlds[(g * 4 + 1) * WPITCH + k] = (_Float16)w.y;
        Wlds[(g * 4 + 2) * WPITCH + k] = (_Float16)w.z;
        Wlds[(g * 4 + 3) * WPITCH + k] = (_Float16)w.w;
      }
    }
  }
  __syncthreads();

  const int lane = tid & 63;
  const int wv = tid >> 6;
  const int q = lane >> 4;
  const int n = lane & 15;
  const int m0 = wv * 16;
  const int gate = n >> 2;
  const int jj = n & 3;
  const int arow = m0 + n;

  f16x8 Bfrag[NXMF + NHMF];  // 48 frags = 192 regs, resident all steps
#pragma unroll
  for (int kk = 0; kk < NXMF + NHMF; ++kk) {
    Bfrag[kk] = *(const f16x8*)(&Wlds[n * WPITCH + kk * 32 + q * 8]);
  }

  const float* bptr[4] = {bf, bi_, bg, bo};
  const float bias_v = bptr[gate][j0 + jj];

  float c_reg[4] = {0.f, 0.f, 0.f, 0.f};

  // x-part GEMM for step t -> acc_x (bias + x contribution). Runs in the
  // barrier-wait window for t>0 (PRE) or just after the poll (fallback).
  f32x4 acc_x;
  auto xpart = [&](int t) {
    f32x4 a = {bias_v, bias_v, bias_v, bias_v};
    f32x4 b = {0.f, 0.f, 0.f, 0.f};
    if constexpr (PRE) {
      const _Float16* ab =
          combx + (size_t)t * B * IN + (size_t)arow * IN + q * 8;
#pragma unroll
      for (int kk = 0; kk < NXMF; kk += 2) {
        f16x8 f0 = *(const f16x8*)(ab + kk * 32);
        f16x8 f1 = *(const f16x8*)(ab + (kk + 1) * 32);
        a = __builtin_amdgcn_mfma_f32_16x16x32_f16(f0, Bfrag[kk], a, 0, 0, 0);
        b = __builtin_amdgcn_mfma_f32_16x16x32_f16(f1, Bfrag[kk + 1], b, 0, 0,
                                                   0);
      }
    } else {
      const _Float16* ab =
          xbuf + (size_t)(t & 1) * B * IN + (size_t)arow * IN + q * 8;
#pragma unroll
      for (int kk = 0; kk < NXMF; kk += 2) {
        f16x8 f0 = load_sc1_16B(ab + kk * 32);
        f16x8 f1 = load_sc1_16B(ab + (kk + 1) * 32);
        a = __builtin_amdgcn_mfma_f32_16x16x32_f16(f0, Bfrag[kk], a, 0, 0, 0);
        b = __builtin_amdgcn_mfma_f32_16x16x32_f16(f1, Bfrag[kk + 1], b, 0, 0,
                                                   0);
      }
    }
    acc_x = a + b;
  };

  xpart(0);

  for (int t = 0; t < T_STEPS; ++t) {
    const _Float16* hb = hbuf + (size_t)(t & 1) * B * H;
    _Float16* hb_next = hbuf + (size_t)((t + 1) & 1) * B * H;

    // ---- h part: sc1 IF-direct loads, 4 accumulator chains ----
    f32x4 a0 = acc_x;
    f32x4 a1 = {0.f, 0.f, 0.f, 0.f};
    f32x4 a2 = {0.f, 0.f, 0.f, 0.f};
    f32x4 a3 = {0.f, 0.f, 0.f, 0.f};
    {
      const _Float16* ab = hb + (size_t)arow * H + q * 8;
#pragma unroll
      for (int kk = 0; kk < NHMF; kk += 4) {
        f16x8 f0 = load_sc1_16B(ab + kk * 32);
        f16x8 f1 = load_sc1_16B(ab + (kk + 1) * 32);
        f16x8 f2 = load_sc1_16B(ab + (kk + 2) * 32);
        f16x8 f3 = load_sc1_16B(ab + (kk + 3) * 32);
        a0 = __builtin_amdgcn_mfma_f32_16x16x32_f16(f0, Bfrag[NXMF + kk], a0,
                                                    0, 0, 0);
        a1 = __builtin_amdgcn_mfma_f32_16x16x32_f16(f1, Bfrag[NXMF + kk + 1],
                                                    a1, 0, 0, 0);
        a2 = __builtin_amdgcn_mfma_f32_16x16x32_f16(f2, Bfrag[NXMF + kk + 2],
                                                    a2, 0, 0, 0);
        a3 = __builtin_amdgcn_mfma_f32_16x16x32_f16(f3, Bfrag[NXMF + kk + 3],
                                                    a3, 0, 0, 0);
      }
    }
    const f32x4 acc = (a0 + a1) + (a2 + a3);

    // ---- epilogue: nonlinearities (all lanes, uniform code) ----
    float v[4];
#pragma unroll
    for (int r = 0; r < 4; ++r) {
      const float z = acc[r];
      v[r] = (gate == 2) ? fast_tanh(z) : fast_sigmoid(z);
    }
    float vi[4], vg[4], vo[4];
#pragma unroll
    for (int r = 0; r < 4; ++r) {
      vi[r] = __shfl(v[r], (lane + 4) & 63, 64);
      vg[r] = __shfl(v[r], (lane + 8) & 63, 64);
      vo[r] = __shfl(v[r], (lane + 12) & 63, 64);
    }
    float hv[4];
#pragma unroll
    for (int r = 0; r < 4; ++r) {
      const float c = fmaf(v[r], c_reg[r], vi[r] * vg[r]);
      c_reg[r] = c;
      hv[r] = vo[r] * fast_tanh(c);
    }
    // gather the 4 contiguous columns (j0..j0+3) onto lane n==0
    float h1[4], h2[4], h3[4];
#pragma unroll
    for (int r = 0; r < 4; ++r) {
      h1[r] = __shfl(hv[r], (lane + 1) & 63, 64);
      h2[r] = __shfl(hv[r], (lane + 2) & 63, 64);
      h3[r] = __shfl(hv[r], (lane + 3) & 63, 64);
    }
    // packed 8B fp16 h-store, sc1 write-through (must precede arrival)
    if (n == 0) {
#pragma unroll
      for (int r = 0; r < 4; ++r) {
        const int b = m0 + q * 4 + r;
        union {
          _Float16 h[4];
          unsigned long long u;
        } pk;
        pk.h[0] = (_Float16)hv[r];
        pk.h[1] = (_Float16)h1[r];
        pk.h[2] = (_Float16)h2[r];
        pk.h[3] = (_Float16)h3[r];
        store_sc1_u64(hb_next + (size_t)b * H + j0, pk.u);
      }
    }

    // ---- fallback: stage x[t+1] into next buffer (sc1 stores) ----
    if (!PRE && t + 1 < T_STEPS && tid < 16) {
      _Float16* xn = xbuf + (size_t)((t + 1) & 1) * B * IN;
      const int row = blk >> 2;
      const int off = (blk & 3) * 128 + tid * 8;
      const float* xs = x + (size_t)(t + 1) * B * IN + (size_t)row * IN + off;
      const float4 x0 = *(const float4*)xs;
      const float4 x1 = *(const float4*)(xs + 4);
      float vals[8] = {x0.x, x0.y, x0.z, x0.w, x1.x, x1.y, x1.z, x1.w};
#pragma unroll
      for (int i = 0; i < 4; ++i) {
        union {
          _Float16 h[2];
          unsigned u;
        } pk;
        pk.h[0] = (_Float16)vals[2 * i];
        pk.h[1] = (_Float16)vals[2 * i + 1];
        store_sc1_u32((unsigned*)(xn + (size_t)row * IN + off + 2 * i), pk.u);
      }
    }

    if (t + 1 < T_STEPS) {
      // drain all this step's sc1 stores (compiler emits vmcnt(0) before
      // s_barrier), then release-publish this block's flag.
      __syncthreads();
      if (tid == 0) store_sc1_u32(bar + blk, (unsigned)(t + 1));
      // out-stores + next-step x GEMM hide under barrier propagation
      if (n == 0) {
#pragma unroll
        for (int r = 0; r < 4; ++r) {
          const int b = m0 + q * 4 + r;
          const float4 o4 = make_float4(hv[r], h1[r], h2[r], h3[r]);
          *(float4*)(out + (size_t)t * B * H + (size_t)b * H + j0) = o4;
        }
      }
      if (PRE) xpart(t + 1);
      // wave 0 scans ALL 256 flags (1KB in 2 u64 loads/lane); waves 1-3
      // wait at a raw barrier (no vmcnt drain).
      if (wv == 0) {
        const unsigned long long* fq = (const unsigned long long*)bar;
        const unsigned tgt = (unsigned)(t + 1);
        for (;;) {
          const unsigned long long p0 = __hip_atomic_load(
              fq + 2 * lane, __ATOMIC_RELAXED, __HIP_MEMORY_SCOPE_AGENT);
          const unsigned long long p1 = __hip_atomic_load(
              fq + 2 * lane + 1, __ATOMIC_RELAXED, __HIP_MEMORY_SCOPE_AGENT);
          const bool ok = ((unsigned)p0 >= tgt) &
                          ((unsigned)(p0 >> 32) >= tgt) &
                          ((unsigned)p1 >= tgt) &
                          ((unsigned)(p1 >> 32) >= tgt);
          if (__all(ok)) break;
          __builtin_amdgcn_s_sleep(1);
        }
      }
      asm volatile("" ::: "memory");
      __builtin_amdgcn_s_barrier();
      asm volatile("" ::: "memory");
      if (!PRE) xpart(t + 1);  // xbuf sc1 loads are safe only post-poll
    } else {
      // final step: out row + hx + cx (no barrier needed)
      float c1[4], c2[4], c3[4];
#pragma unroll
      for (int r = 0; r < 4; ++r) {
        c1[r] = __shfl(c_reg[r], (lane + 1) & 63, 64);
        c2[r] = __shfl(c_reg[r], (lane + 2) & 63, 64);
        c3[r] = __shfl(c_reg[r], (lane + 3) & 63, 64);
      }
      if (n == 0) {
#pragma unroll
        for (int r = 0; r < 4; ++r) {
          const int b = m0 + q * 4 + r;
          const float4 o4 = make_float4(hv[r], h1[r], h2[r], h3[r]);
          *(float4*)(out + (size_t)t * B * H + (size_t)b * H + j0) = o4;
          *(float4*)(out + (size_t)T_STEPS * B * H + (size_t)b * H + j0) =
              o4;  // hx
          const float4 c4 = make_float4(c_reg[r], c1[r], c2[r], c3[r]);
          *(float4*)(out + (size_t)T_STEPS * B * H + (size_t)B * H +
                     (size_t)b * H + j0) = c4;  // cx
        }
      }
    }
  }
}

}  // namespace

extern "C" void kernel_launch(void* const* d_in, const int* in_sizes, int n_in,
                              void* d_out, int out_size, void* d_ws,
                              size_t ws_size, hipStream_t stream) {
  const float* x = (const float*)d_in[0];
  const float* Wf = (const float*)d_in[1];
  const float* bf = (const float*)d_in[2];
  const float* Wi = (const float*)d_in[3];
  const float* bi = (const float*)d_in[4];
  const float* Wg = (const float*)d_in[5];
  const float* bg = (const float*)d_in[6];
  const float* Wo = (const float*)d_in[7];
  const float* bo = (const float*)d_in[8];
  float* out = (float*)d_out;

  char* ws = (char*)d_ws;
  _Float16* hbuf = (_Float16*)(ws + HBUF_OFF);
  _Float16* xbuf = (_Float16*)(ws + XBUF_OFF);
  unsigned* bar = (unsigned*)(ws + BAR_OFF);
  _Float16* combx = (_Float16*)(ws + COMBX_OFF);

  const bool pre = ws_size >= NEED_PRE;

  if (pre) {
    const size_t n = (size_t)T_STEPS * B * IN;
    prep_pre<<<(unsigned)((n + 255) / 256), 256, 0, stream>>>(x, combx, hbuf,
                                                              bar);
    lstm_persist<true><<<NBLK, 256, 0, stream>>>(
        x, Wf, Wi, Wg, Wo, bf, bi, bg, bo, out, combx, xbuf, hbuf, bar);
  } else {
    prep_fb<<<(2 * B * H + 255) / 256, 256, 0, stream>>>(x, xbuf, hbuf, bar);
    lstm_persist<false><<<NBLK, 256, 0, stream>>>(
        x, Wf, Wi, Wg, Wo, bf, bi, bg, bo, out, combx, xbuf, hbuf, bar);
  }
}

// Round 4
// 4053.881 us; speedup vs baseline: 1.5182x; 1.5182x over previous
//
#include <hip/hip_runtime.h>
#include <math.h>

// Persistent fp16-MFMA LSTM, round 7. T=512, B=64, IN=512, H=1024, K=1536.
// 256 blocks x 256 threads (1 block/CU). Changes vs round 6:
//  - 2-D re-tile: 4 batch-groups x 64 j-groups. Block (bgrp=blk&3,
//    jgrp=blk>>2) owns batch rows [16*bgrp,16*bgrp+16) x j-cols
//    [16*jgrp,16*jgrp+16) (4 j-cols per wave x 4 gates). LSTM rows are
//    batch-independent, so groups share NO data:
//      * h read per block per step: 128 KB -> 32 KB (staged once into LDS,
//        all 4 waves ds_read it; chip IF h-traffic 32 MB -> 8 MB/step).
//      * barrier participants: 256 -> 64, four independent group barriers
//        (4 counter lines + 8 flag replicas each); groups drift freely.
//  - barrier reverted to the r5 scheme (counter RMW by wave-1 lane 0, last
//    arriver publishes replicated flags, wave 0 polls, raw s_barrier) --
//    r6's all-scan regressed.
//  - W one-time staging done in 4 chunks (one per wave's 16 cols).
//  - unchanged: out-stores + xpart(t+1) hidden in the wait window, 4-chain
//    h-MFMA, 2-chain x-MFMA, packed 8B h-stores, fast sigmoid/tanh.

namespace {

constexpr int T_STEPS = 512;
constexpr int B = 64;
constexpr int IN = 512;
constexpr int H = 1024;
constexpr int K = IN + H;    // 1536
constexpr int NBLK = 256;
constexpr int NXMF = IN / 32;  // 16 x-part MFMAs
constexpr int NHMF = H / 32;   // 32 h-part MFMAs
constexpr int WPITCH = K + 8;  // one-time W staging pitch (halves)
constexpr int HPITCH = H + 8;  // per-step h staging pitch (halves)

// ws layout (bytes) — unchanged so NEED_PRE is identical.
constexpr size_t HBUF_OFF = 0;                                  // 2*B*H fp16
constexpr size_t XBUF_OFF = HBUF_OFF + 2ull * B * H * 2;        // 2*B*IN fp16
constexpr size_t BAR_OFF = XBUF_OFF + 2ull * B * IN * 2;        // 1056 uints
constexpr size_t COMBX_OFF = BAR_OFF + 1056ull * 4;             // T*B*IN fp16
constexpr size_t NEED_PRE = COMBX_OFF + (size_t)T_STEPS * B * IN * 2;

typedef __attribute__((ext_vector_type(8))) _Float16 f16x8;
typedef __attribute__((ext_vector_type(4))) float f32x4;

__device__ __forceinline__ f16x8 load_sc1_16B(const _Float16* p) {
  union {
    unsigned long long u[2];
    f16x8 v;
  } cv;
  const unsigned long long* q = (const unsigned long long*)p;
  cv.u[0] = __hip_atomic_load(q, __ATOMIC_RELAXED, __HIP_MEMORY_SCOPE_AGENT);
  cv.u[1] =
      __hip_atomic_load(q + 1, __ATOMIC_RELAXED, __HIP_MEMORY_SCOPE_AGENT);
  return cv.v;
}

__device__ __forceinline__ void store_sc1_u64(_Float16* p,
                                              unsigned long long v) {
  __hip_atomic_store((unsigned long long*)p, v, __ATOMIC_RELAXED,
                     __HIP_MEMORY_SCOPE_AGENT);
}

__device__ __forceinline__ void store_sc1_u32(unsigned* p, unsigned v) {
  __hip_atomic_store(p, v, __ATOMIC_RELAXED, __HIP_MEMORY_SCOPE_AGENT);
}

// |err| ~1e-7 relative — far below the fp16 h quantization already present.
__device__ __forceinline__ float fast_sigmoid(float z) {
  return __builtin_amdgcn_rcpf(1.0f + __expf(-z));
}
__device__ __forceinline__ float fast_tanh(float z) {
  return 1.0f - 2.0f * __builtin_amdgcn_rcpf(1.0f + __expf(2.0f * z));
}

// Prefilled-mode prep: combx[t][b][k] = fp16(x), zero hbuf, zero barrier.
__global__ void prep_pre(const float* __restrict__ x,
                         _Float16* __restrict__ combx,
                         _Float16* __restrict__ hbuf,
                         unsigned* __restrict__ bar) {
  const size_t i = (size_t)blockIdx.x * 256 + threadIdx.x;
  if (i < (size_t)T_STEPS * B * IN) combx[i] = (_Float16)x[i];
  if (i < 2ull * B * H) hbuf[i] = (_Float16)0.f;
  if (i < 1056) bar[i] = 0u;
}

// Fallback prep: xbuf[0] = fp16(x[0]), zero hbuf, zero barrier.
__global__ void prep_fb(const float* __restrict__ x,
                        _Float16* __restrict__ xbuf,
                        _Float16* __restrict__ hbuf,
                        unsigned* __restrict__ bar) {
  const size_t i = (size_t)blockIdx.x * 256 + threadIdx.x;
  if (i < (size_t)B * IN) xbuf[i] = (_Float16)x[i];
  if (i < 2ull * B * H) hbuf[i] = (_Float16)0.f;
  if (i < 1056) bar[i] = 0u;
}

template <bool PRE>
__global__ __launch_bounds__(256, 1) void lstm_persist(
    const float* __restrict__ x, const float* __restrict__ Wf,
    const float* __restrict__ Wi, const float* __restrict__ Wg,
    const float* __restrict__ Wo, const float* __restrict__ bf,
    const float* __restrict__ bi_, const float* __restrict__ bg,
    const float* __restrict__ bo, float* __restrict__ out,
    _Float16* __restrict__ combx, _Float16* __restrict__ xbuf,
    _Float16* __restrict__ hbuf, unsigned* __restrict__ bar) {
  __shared__ _Float16 Wlds[16 * WPITCH];  // one-time W staging
  __shared__ _Float16 Hlds[16 * HPITCH];  // per-step h staging (33 KB)

  const int blk = blockIdx.x;
  const int tid = threadIdx.x;
  const int bgrp = blk & 3;    // batch group: rows [16*bgrp, 16*bgrp+16)
  const int jgrp = blk >> 2;   // j group: cols [16*jgrp, 16*jgrp+16)
  const int jbase = jgrp * 16;

  const int lane = tid & 63;
  const int wv = tid >> 6;
  const int q = lane >> 4;
  const int n = lane & 15;
  const int gate = n >> 2;
  const int jj = n & 3;
  const int j0w = jbase + wv * 4;  // this wave's 4 output cols
  const int brow0 = bgrp * 16;     // first batch row of this block

  // ---- one-time: stage W in 4 chunks (16 cols each), lift B-frags ----
  f16x8 Bfrag[NXMF + NHMF];  // 48 frags, resident all steps
  {
    const float* wptr[4] = {Wf, Wi, Wg, Wo};
    for (int c = 0; c < 4; ++c) {
#pragma unroll
      for (int g = 0; g < 4; ++g) {
        const float* wsrc = wptr[g];
        for (int it = 0; it < K / 256; ++it) {
          const int k = it * 256 + tid;
          const float4 w = *(const float4*)(wsrc + (size_t)k * H + jbase + c * 4);
          Wlds[(g * 4 + 0) * WPITCH + k] = (_Float16)w.x;
          Wlds[(g * 4 + 1) * WPITCH + k] = (_Float16)w.y;
          Wlds[(g * 4 + 2) * WPITCH + k] = (_Float16)w.z;
          Wlds[(g * 4 + 3) * WPITCH + k] = (_Float16)w.w;
        }
      }
      __syncthreads();
      if (wv == c) {
#pragma unroll
        for (int kk = 0; kk < NXMF + NHMF; ++kk) {
          Bfrag[kk] = *(const f16x8*)(&Wlds[n * WPITCH + kk * 32 + q * 8]);
        }
      }
      __syncthreads();
    }
  }

  const float* bptr[4] = {bf, bi_, bg, bo};
  const float bias_v = bptr[gate][j0w + jj];

  float c_reg[4] = {0.f, 0.f, 0.f, 0.f};

  // per-group barrier state: counter line + 8 replicated flag lines
  unsigned* cnt = bar + bgrp * 16;                              // 64B spacing
  unsigned* flagp = bar + 64 + (bgrp * 8 + ((blk >> 3) & 7)) * 16;

  // x-part GEMM for step t -> acc_x (bias + x contribution). Runs in the
  // barrier-wait window for t>0 (PRE) or just after the poll (fallback).
  f32x4 acc_x;
  auto xpart = [&](int t) {
    f32x4 a = {bias_v, bias_v, bias_v, bias_v};
    f32x4 b = {0.f, 0.f, 0.f, 0.f};
    if constexpr (PRE) {
      const _Float16* ab =
          combx + (size_t)t * B * IN + (size_t)(brow0 + n) * IN + q * 8;
#pragma unroll
      for (int kk = 0; kk < NXMF; kk += 2) {
        f16x8 f0 = *(const f16x8*)(ab + kk * 32);
        f16x8 f1 = *(const f16x8*)(ab + (kk + 1) * 32);
        a = __builtin_amdgcn_mfma_f32_16x16x32_f16(f0, Bfrag[kk], a, 0, 0, 0);
        b = __builtin_amdgcn_mfma_f32_16x16x32_f16(f1, Bfrag[kk + 1], b, 0, 0,
                                                   0);
      }
    } else {
      const _Float16* ab =
          xbuf + (size_t)(t & 1) * B * IN + (size_t)(brow0 + n) * IN + q * 8;
#pragma unroll
      for (int kk = 0; kk < NXMF; kk += 2) {
        f16x8 f0 = load_sc1_16B(ab + kk * 32);
        f16x8 f1 = load_sc1_16B(ab + (kk + 1) * 32);
        a = __builtin_amdgcn_mfma_f32_16x16x32_f16(f0, Bfrag[kk], a, 0, 0, 0);
        b = __builtin_amdgcn_mfma_f32_16x16x32_f16(f1, Bfrag[kk + 1], b, 0, 0,
                                                   0);
      }
    }
    acc_x = a + b;
  };

  xpart(0);

  for (int t = 0; t < T_STEPS; ++t) {
    const _Float16* hb =
        hbuf + (size_t)(t & 1) * B * H + (size_t)brow0 * H;
    _Float16* hb_next = hbuf + (size_t)((t + 1) & 1) * B * H;

    // ---- stage h[t] (16 rows x 1024) into LDS: 8 x 16B sc1 loads/thread ----
    {
#pragma unroll
      for (int i = 0; i < 8; ++i) {
        const int g2 = tid + i * 256;     // granule 0..2047
        const int row = g2 >> 7;          // 0..15
        const int c16 = g2 & 127;         // 16B granule within row
        f16x8 v = load_sc1_16B(hb + (size_t)row * H + c16 * 8);
        *(f16x8*)(&Hlds[row * HPITCH + c16 * 8]) = v;
      }
    }
    __syncthreads();

    // ---- h part: LDS ds_read_b128, 4 accumulator chains ----
    f32x4 a0 = acc_x;
    f32x4 a1 = {0.f, 0.f, 0.f, 0.f};
    f32x4 a2 = {0.f, 0.f, 0.f, 0.f};
    f32x4 a3 = {0.f, 0.f, 0.f, 0.f};
    {
      const _Float16* hl = &Hlds[n * HPITCH + q * 8];
#pragma unroll
      for (int kk = 0; kk < NHMF; kk += 4) {
        f16x8 f0 = *(const f16x8*)(hl + kk * 32);
        f16x8 f1 = *(const f16x8*)(hl + (kk + 1) * 32);
        f16x8 f2 = *(const f16x8*)(hl + (kk + 2) * 32);
        f16x8 f3 = *(const f16x8*)(hl + (kk + 3) * 32);
        a0 = __builtin_amdgcn_mfma_f32_16x16x32_f16(f0, Bfrag[NXMF + kk], a0,
                                                    0, 0, 0);
        a1 = __builtin_amdgcn_mfma_f32_16x16x32_f16(f1, Bfrag[NXMF + kk + 1],
                                                    a1, 0, 0, 0);
        a2 = __builtin_amdgcn_mfma_f32_16x16x32_f16(f2, Bfrag[NXMF + kk + 2],
                                                    a2, 0, 0, 0);
        a3 = __builtin_amdgcn_mfma_f32_16x16x32_f16(f3, Bfrag[NXMF + kk + 3],
                                                    a3, 0, 0, 0);
      }
    }
    const f32x4 acc = (a0 + a1) + (a2 + a3);

    // ---- epilogue: nonlinearities (all lanes, uniform code) ----
    float v[4];
#pragma unroll
    for (int r = 0; r < 4; ++r) {
      const float z = acc[r];
      v[r] = (gate == 2) ? fast_tanh(z) : fast_sigmoid(z);
    }
    float vi[4], vg[4], vo[4];
#pragma unroll
    for (int r = 0; r < 4; ++r) {
      vi[r] = __shfl(v[r], (lane + 4) & 63, 64);
      vg[r] = __shfl(v[r], (lane + 8) & 63, 64);
      vo[r] = __shfl(v[r], (lane + 12) & 63, 64);
    }
    float hv[4];
#pragma unroll
    for (int r = 0; r < 4; ++r) {
      const float c = fmaf(v[r], c_reg[r], vi[r] * vg[r]);
      c_reg[r] = c;
      hv[r] = vo[r] * fast_tanh(c);
    }
    // gather the 4 contiguous columns (j0w..j0w+3) onto lane n==0
    float h1[4], h2[4], h3[4];
#pragma unroll
    for (int r = 0; r < 4; ++r) {
      h1[r] = __shfl(hv[r], (lane + 1) & 63, 64);
      h2[r] = __shfl(hv[r], (lane + 2) & 63, 64);
      h3[r] = __shfl(hv[r], (lane + 3) & 63, 64);
    }
    // packed 8B fp16 h-store, sc1 write-through (must precede arrival)
    if (n == 0) {
#pragma unroll
      for (int r = 0; r < 4; ++r) {
        const int b = brow0 + q * 4 + r;
        union {
          _Float16 h[4];
          unsigned long long u;
        } pk;
        pk.h[0] = (_Float16)hv[r];
        pk.h[1] = (_Float16)h1[r];
        pk.h[2] = (_Float16)h2[r];
        pk.h[3] = (_Float16)h3[r];
        store_sc1_u64(hb_next + (size_t)b * H + j0w, pk.u);
      }
    }

    // ---- fallback: stage x[t+1] rows of OWN group into next buffer ----
    if (!PRE && t + 1 < T_STEPS && tid < 16) {
      _Float16* xn = xbuf + (size_t)((t + 1) & 1) * B * IN;
      const int row = brow0 + (jgrp >> 2);         // 4 blocks per row
      const int off = (jgrp & 3) * 128 + tid * 8;  // quarter of 512
      const float* xs = x + (size_t)(t + 1) * B * IN + (size_t)row * IN + off;
      const float4 x0 = *(const float4*)xs;
      const float4 x1 = *(const float4*)(xs + 4);
      float vals[8] = {x0.x, x0.y, x0.z, x0.w, x1.x, x1.y, x1.z, x1.w};
#pragma unroll
      for (int i = 0; i < 4; ++i) {
        union {
          _Float16 h[2];
          unsigned u;
        } pk;
        pk.h[0] = (_Float16)vals[2 * i];
        pk.h[1] = (_Float16)vals[2 * i + 1];
        store_sc1_u32((unsigned*)(xn + (size_t)row * IN + off + 2 * i), pk.u);
      }
    }

    if (t + 1 < T_STEPS) {
      // drain this step's sc1 stores (compiler emits vmcnt(0) before
      // s_barrier), then arrive at the GROUP barrier (64 blocks).
      __syncthreads();
      if (tid == 64) {  // wave-1 lane 0 arrives; wave 0 stays unstalled
        const unsigned a = __hip_atomic_fetch_add(cnt, 1u, __ATOMIC_RELAXED,
                                                  __HIP_MEMORY_SCOPE_AGENT);
        if (a == 64u * (unsigned)(t + 1) - 1u) {
#pragma unroll
          for (int i = 0; i < 8; ++i)
            store_sc1_u32(bar + 64 + (bgrp * 8 + i) * 16, (unsigned)(t + 1));
        }
      }
      // out-stores + next-step x GEMM hide under barrier propagation
      if (n == 0) {
#pragma unroll
        for (int r = 0; r < 4; ++r) {
          const int b = brow0 + q * 4 + r;
          const float4 o4 = make_float4(hv[r], h1[r], h2[r], h3[r]);
          *(float4*)(out + (size_t)t * B * H + (size_t)b * H + j0w) = o4;
        }
      }
      if (PRE) xpart(t + 1);
      // wave 0 polls this group's flag replica; waves 1-3 wait at a raw
      // barrier (no vmcnt drain).
      if (wv == 0) {
        while (__hip_atomic_load(flagp, __ATOMIC_RELAXED,
                                 __HIP_MEMORY_SCOPE_AGENT) <
               (unsigned)(t + 1)) {
          __builtin_amdgcn_s_sleep(1);
        }
      }
      asm volatile("" ::: "memory");
      __builtin_amdgcn_s_barrier();
      asm volatile("" ::: "memory");
      if (!PRE) xpart(t + 1);  // xbuf sc1 loads are safe only post-poll
    } else {
      // final step: out row + hx + cx (no barrier needed)
      float c1[4], c2[4], c3[4];
#pragma unroll
      for (int r = 0; r < 4; ++r) {
        c1[r] = __shfl(c_reg[r], (lane + 1) & 63, 64);
        c2[r] = __shfl(c_reg[r], (lane + 2) & 63, 64);
        c3[r] = __shfl(c_reg[r], (lane + 3) & 63, 64);
      }
      if (n == 0) {
#pragma unroll
        for (int r = 0; r < 4; ++r) {
          const int b = brow0 + q * 4 + r;
          const float4 o4 = make_float4(hv[r], h1[r], h2[r], h3[r]);
          *(float4*)(out + (size_t)t * B * H + (size_t)b * H + j0w) = o4;
          *(float4*)(out + (size_t)T_STEPS * B * H + (size_t)b * H + j0w) =
              o4;  // hx
          const float4 c4 = make_float4(c_reg[r], c1[r], c2[r], c3[r]);
          *(float4*)(out + (size_t)T_STEPS * B * H + (size_t)B * H +
                     (size_t)b * H + j0w) = c4;  // cx
        }
      }
    }
  }
}

}  // namespace

extern "C" void kernel_launch(void* const* d_in, const int* in_sizes, int n_in,
                              void* d_out, int out_size, void* d_ws,
                              size_t ws_size, hipStream_t stream) {
  const float* x = (const float*)d_in[0];
  const float* Wf = (const float*)d_in[1];
  const float* bf = (const float*)d_in[2];
  const float* Wi = (const float*)d_in[3];
  const float* bi = (const float*)d_in[4];
  const float* Wg = (const float*)d_in[5];
  const float* bg = (const float*)d_in[6];
  const float* Wo = (const float*)d_in[7];
  const float* bo = (const float*)d_in[8];
  float* out = (float*)d_out;

  char* ws = (char*)d_ws;
  _Float16* hbuf = (_Float16*)(ws + HBUF_OFF);
  _Float16* xbuf = (_Float16*)(ws + XBUF_OFF);
  unsigned* bar = (unsigned*)(ws + BAR_OFF);
  _Float16* combx = (_Float16*)(ws + COMBX_OFF);

  const bool pre = ws_size >= NEED_PRE;

  if (pre) {
    const size_t n = (size_t)T_STEPS * B * IN;
    prep_pre<<<(unsigned)((n + 255) / 256), 256, 0, stream>>>(x, combx, hbuf,
                                                              bar);
    lstm_persist<true><<<NBLK, 256, 0, stream>>>(
        x, Wf, Wi, Wg, Wo, bf, bi, bg, bo, out, combx, xbuf, hbuf, bar);
  } else {
    prep_fb<<<(2 * B * H + 255) / 256, 256, 0, stream>>>(x, xbuf, hbuf, bar);
    lstm_persist<false><<<NBLK, 256, 0, stream>>>(
        x, Wf, Wi, Wg, Wo, bf, bi, bg, bo, out, combx, xbuf, hbuf, bar);
  }
}

// Round 5
// 3391.709 us; speedup vs baseline: 1.8146x; 1.1952x over previous
//
#include <hip/hip_runtime.h>
#include <math.h>

// Persistent fp16-MFMA LSTM, round 8. T=512, B=64, IN=512, H=1024, K=1536.
// 256 blocks x 256 threads (1 block/CU). Changes vs round 7:
//  - ALL-SCAN group barrier: each block release-stores flags[bgrp][jgrp]=t+1
//    after the drain; consumer wave 0 polls its group's 64 flags with ONE
//    u32 agent load per lane (4 cache lines per CU). Deletes the 64-way
//    serialized fetch_add, the RMW-return stall, and the publish hop.
//    (r6's all-scan failed at 256 blocks x 16 lines; this is 64 x 4 lines.)
//  - split-K pipelined h staging: loads i=0..3 cover K-halves [0,512),
//    i=4..7 cover [512,1024) (each wave still loads contiguous 1KB rows).
//    Write A -> sync -> MFMA(A) while B loads land -> write B -> sync ->
//    MFMA(B). Hides ~half the IF staging latency under MFMA work.
//  - unchanged: 2-D tile (4 batch-groups x 64 j-groups), out-stores +
//    xpart(t+1) in the wait window, packed 8B h-stores, fast sigmoid/tanh.

namespace {

constexpr int T_STEPS = 512;
constexpr int B = 64;
constexpr int IN = 512;
constexpr int H = 1024;
constexpr int K = IN + H;    // 1536
constexpr int NBLK = 256;
constexpr int NXMF = IN / 32;  // 16 x-part MFMAs
constexpr int NHMF = H / 32;   // 32 h-part MFMAs
constexpr int WPITCH = K + 8;  // one-time W staging pitch (halves)
constexpr int HPITCH = H + 8;  // per-step h staging pitch (halves)

// ws layout (bytes) — unchanged so NEED_PRE is identical.
constexpr size_t HBUF_OFF = 0;                                  // 2*B*H fp16
constexpr size_t XBUF_OFF = HBUF_OFF + 2ull * B * H * 2;        // 2*B*IN fp16
constexpr size_t BAR_OFF = XBUF_OFF + 2ull * B * IN * 2;        // 1056 uints
constexpr size_t COMBX_OFF = BAR_OFF + 1056ull * 4;             // T*B*IN fp16
constexpr size_t NEED_PRE = COMBX_OFF + (size_t)T_STEPS * B * IN * 2;

typedef __attribute__((ext_vector_type(8))) _Float16 f16x8;
typedef __attribute__((ext_vector_type(4))) float f32x4;

__device__ __forceinline__ f16x8 load_sc1_16B(const _Float16* p) {
  union {
    unsigned long long u[2];
    f16x8 v;
  } cv;
  const unsigned long long* q = (const unsigned long long*)p;
  cv.u[0] = __hip_atomic_load(q, __ATOMIC_RELAXED, __HIP_MEMORY_SCOPE_AGENT);
  cv.u[1] =
      __hip_atomic_load(q + 1, __ATOMIC_RELAXED, __HIP_MEMORY_SCOPE_AGENT);
  return cv.v;
}

__device__ __forceinline__ void store_sc1_u64(_Float16* p,
                                              unsigned long long v) {
  __hip_atomic_store((unsigned long long*)p, v, __ATOMIC_RELAXED,
                     __HIP_MEMORY_SCOPE_AGENT);
}

__device__ __forceinline__ void store_sc1_u32(unsigned* p, unsigned v) {
  __hip_atomic_store(p, v, __ATOMIC_RELAXED, __HIP_MEMORY_SCOPE_AGENT);
}

// |err| ~1e-7 relative — far below the fp16 h quantization already present.
__device__ __forceinline__ float fast_sigmoid(float z) {
  return __builtin_amdgcn_rcpf(1.0f + __expf(-z));
}
__device__ __forceinline__ float fast_tanh(float z) {
  return 1.0f - 2.0f * __builtin_amdgcn_rcpf(1.0f + __expf(2.0f * z));
}

// Prefilled-mode prep: combx[t][b][k] = fp16(x), zero hbuf, zero barrier.
__global__ void prep_pre(const float* __restrict__ x,
                         _Float16* __restrict__ combx,
                         _Float16* __restrict__ hbuf,
                         unsigned* __restrict__ bar) {
  const size_t i = (size_t)blockIdx.x * 256 + threadIdx.x;
  if (i < (size_t)T_STEPS * B * IN) combx[i] = (_Float16)x[i];
  if (i < 2ull * B * H) hbuf[i] = (_Float16)0.f;
  if (i < 1056) bar[i] = 0u;
}

// Fallback prep: xbuf[0] = fp16(x[0]), zero hbuf, zero barrier.
__global__ void prep_fb(const float* __restrict__ x,
                        _Float16* __restrict__ xbuf,
                        _Float16* __restrict__ hbuf,
                        unsigned* __restrict__ bar) {
  const size_t i = (size_t)blockIdx.x * 256 + threadIdx.x;
  if (i < (size_t)B * IN) xbuf[i] = (_Float16)x[i];
  if (i < 2ull * B * H) hbuf[i] = (_Float16)0.f;
  if (i < 1056) bar[i] = 0u;
}

template <bool PRE>
__global__ __launch_bounds__(256, 1) void lstm_persist(
    const float* __restrict__ x, const float* __restrict__ Wf,
    const float* __restrict__ Wi, const float* __restrict__ Wg,
    const float* __restrict__ Wo, const float* __restrict__ bf,
    const float* __restrict__ bi_, const float* __restrict__ bg,
    const float* __restrict__ bo, float* __restrict__ out,
    _Float16* __restrict__ combx, _Float16* __restrict__ xbuf,
    _Float16* __restrict__ hbuf, unsigned* __restrict__ bar) {
  __shared__ _Float16 Wlds[16 * WPITCH];  // one-time W staging
  __shared__ _Float16 Hlds[16 * HPITCH];  // per-step h staging (33 KB)

  const int blk = blockIdx.x;
  const int tid = threadIdx.x;
  const int bgrp = blk & 3;    // batch group: rows [16*bgrp, 16*bgrp+16)
  const int jgrp = blk >> 2;   // j group: cols [16*jgrp, 16*jgrp+16)
  const int jbase = jgrp * 16;

  const int lane = tid & 63;
  const int wv = tid >> 6;
  const int q = lane >> 4;
  const int n = lane & 15;
  const int gate = n >> 2;
  const int jj = n & 3;
  const int j0w = jbase + wv * 4;  // this wave's 4 output cols
  const int brow0 = bgrp * 16;     // first batch row of this block

  // ---- one-time: stage W in 4 chunks (4 cols x 4 gates each), lift ----
  f16x8 Bfrag[NXMF + NHMF];  // 48 frags, resident all steps
  {
    const float* wptr[4] = {Wf, Wi, Wg, Wo};
    for (int c = 0; c < 4; ++c) {
#pragma unroll
      for (int g = 0; g < 4; ++g) {
        const float* wsrc = wptr[g];
        for (int it = 0; it < K / 256; ++it) {
          const int k = it * 256 + tid;
          const float4 w =
              *(const float4*)(wsrc + (size_t)k * H + jbase + c * 4);
          Wlds[(g * 4 + 0) * WPITCH + k] = (_Float16)w.x;
          Wlds[(g * 4 + 1) * WPITCH + k] = (_Float16)w.y;
          Wlds[(g * 4 + 2) * WPITCH + k] = (_Float16)w.z;
          Wlds[(g * 4 + 3) * WPITCH + k] = (_Float16)w.w;
        }
      }
      __syncthreads();
      if (wv == c) {
#pragma unroll
        for (int kk = 0; kk < NXMF + NHMF; ++kk) {
          Bfrag[kk] = *(const f16x8*)(&Wlds[n * WPITCH + kk * 32 + q * 8]);
        }
      }
      __syncthreads();
    }
  }

  const float* bptr[4] = {bf, bi_, bg, bo};
  const float bias_v = bptr[gate][j0w + jj];

  float c_reg[4] = {0.f, 0.f, 0.f, 0.f};

  // all-scan barrier state: 64 u32 flags per group (4 cache lines)
  unsigned* flags = bar + bgrp * 64;

  // x-part GEMM for step t -> acc_x (bias + x contribution). Runs in the
  // barrier-wait window for t>0 (PRE) or just after the poll (fallback).
  f32x4 acc_x;
  auto xpart = [&](int t) {
    f32x4 a = {bias_v, bias_v, bias_v, bias_v};
    f32x4 b = {0.f, 0.f, 0.f, 0.f};
    if constexpr (PRE) {
      const _Float16* ab =
          combx + (size_t)t * B * IN + (size_t)(brow0 + n) * IN + q * 8;
#pragma unroll
      for (int kk = 0; kk < NXMF; kk += 2) {
        f16x8 f0 = *(const f16x8*)(ab + kk * 32);
        f16x8 f1 = *(const f16x8*)(ab + (kk + 1) * 32);
        a = __builtin_amdgcn_mfma_f32_16x16x32_f16(f0, Bfrag[kk], a, 0, 0, 0);
        b = __builtin_amdgcn_mfma_f32_16x16x32_f16(f1, Bfrag[kk + 1], b, 0, 0,
                                                   0);
      }
    } else {
      const _Float16* ab =
          xbuf + (size_t)(t & 1) * B * IN + (size_t)(brow0 + n) * IN + q * 8;
#pragma unroll
      for (int kk = 0; kk < NXMF; kk += 2) {
        f16x8 f0 = load_sc1_16B(ab + kk * 32);
        f16x8 f1 = load_sc1_16B(ab + (kk + 1) * 32);
        a = __builtin_amdgcn_mfma_f32_16x16x32_f16(f0, Bfrag[kk], a, 0, 0, 0);
        b = __builtin_amdgcn_mfma_f32_16x16x32_f16(f1, Bfrag[kk + 1], b, 0, 0,
                                                   0);
      }
    }
    acc_x = a + b;
  };

  xpart(0);

  for (int t = 0; t < T_STEPS; ++t) {
    const _Float16* hb = hbuf + (size_t)(t & 1) * B * H + (size_t)brow0 * H;
    _Float16* hb_next = hbuf + (size_t)((t + 1) & 1) * B * H;

    // ---- stage h[t] (16 rows x 1024): split-K pipelined A/B halves ----
    // A: K-halves [0,512), B: [512,1024). Each wave's 4 loads per half are
    // 1KB contiguous within a row (coalesced).
    f16x8 va[4], vb[4];
#pragma unroll
    for (int i = 0; i < 4; ++i) {
      const int g = tid + i * 256;  // 0..1023
      const int row = g >> 6;       // 0..15
      const int c16 = g & 63;       // 16B granule within half-row
      va[i] = load_sc1_16B(hb + (size_t)row * H + c16 * 8);
    }
#pragma unroll
    for (int i = 0; i < 4; ++i) {
      const int g = tid + i * 256;
      const int row = g >> 6;
      const int c16 = g & 63;
      vb[i] = load_sc1_16B(hb + (size_t)row * H + 512 + c16 * 8);
    }
#pragma unroll
    for (int i = 0; i < 4; ++i) {
      const int g = tid + i * 256;
      const int row = g >> 6;
      const int c16 = g & 63;
      *(f16x8*)(&Hlds[row * HPITCH + c16 * 8]) = va[i];
    }
    __syncthreads();

    // ---- h part A: kk 0..15 while B loads land ----
    f32x4 a0 = acc_x;
    f32x4 a1 = {0.f, 0.f, 0.f, 0.f};
    f32x4 a2 = {0.f, 0.f, 0.f, 0.f};
    f32x4 a3 = {0.f, 0.f, 0.f, 0.f};
    {
      const _Float16* hl = &Hlds[n * HPITCH + q * 8];
#pragma unroll
      for (int kk = 0; kk < NHMF / 2; kk += 4) {
        f16x8 f0 = *(const f16x8*)(hl + kk * 32);
        f16x8 f1 = *(const f16x8*)(hl + (kk + 1) * 32);
        f16x8 f2 = *(const f16x8*)(hl + (kk + 2) * 32);
        f16x8 f3 = *(const f16x8*)(hl + (kk + 3) * 32);
        a0 = __builtin_amdgcn_mfma_f32_16x16x32_f16(f0, Bfrag[NXMF + kk], a0,
                                                    0, 0, 0);
        a1 = __builtin_amdgcn_mfma_f32_16x16x32_f16(f1, Bfrag[NXMF + kk + 1],
                                                    a1, 0, 0, 0);
        a2 = __builtin_amdgcn_mfma_f32_16x16x32_f16(f2, Bfrag[NXMF + kk + 2],
                                                    a2, 0, 0, 0);
        a3 = __builtin_amdgcn_mfma_f32_16x16x32_f16(f3, Bfrag[NXMF + kk + 3],
                                                    a3, 0, 0, 0);
      }
    }
    // write B half, sync, consume
#pragma unroll
    for (int i = 0; i < 4; ++i) {
      const int g = tid + i * 256;
      const int row = g >> 6;
      const int c16 = g & 63;
      *(f16x8*)(&Hlds[row * HPITCH + 512 + c16 * 8]) = vb[i];
    }
    __syncthreads();
    {
      const _Float16* hl = &Hlds[n * HPITCH + q * 8];
#pragma unroll
      for (int kk = NHMF / 2; kk < NHMF; kk += 4) {
        f16x8 f0 = *(const f16x8*)(hl + kk * 32);
        f16x8 f1 = *(const f16x8*)(hl + (kk + 1) * 32);
        f16x8 f2 = *(const f16x8*)(hl + (kk + 2) * 32);
        f16x8 f3 = *(const f16x8*)(hl + (kk + 3) * 32);
        a0 = __builtin_amdgcn_mfma_f32_16x16x32_f16(f0, Bfrag[NXMF + kk], a0,
                                                    0, 0, 0);
        a1 = __builtin_amdgcn_mfma_f32_16x16x32_f16(f1, Bfrag[NXMF + kk + 1],
                                                    a1, 0, 0, 0);
        a2 = __builtin_amdgcn_mfma_f32_16x16x32_f16(f2, Bfrag[NXMF + kk + 2],
                                                    a2, 0, 0, 0);
        a3 = __builtin_amdgcn_mfma_f32_16x16x32_f16(f3, Bfrag[NXMF + kk + 3],
                                                    a3, 0, 0, 0);
      }
    }
    const f32x4 acc = (a0 + a1) + (a2 + a3);

    // ---- epilogue: nonlinearities (all lanes, uniform code) ----
    float v[4];
#pragma unroll
    for (int r = 0; r < 4; ++r) {
      const float z = acc[r];
      v[r] = (gate == 2) ? fast_tanh(z) : fast_sigmoid(z);
    }
    float vi[4], vg[4], vo[4];
#pragma unroll
    for (int r = 0; r < 4; ++r) {
      vi[r] = __shfl(v[r], (lane + 4) & 63, 64);
      vg[r] = __shfl(v[r], (lane + 8) & 63, 64);
      vo[r] = __shfl(v[r], (lane + 12) & 63, 64);
    }
    float hv[4];
#pragma unroll
    for (int r = 0; r < 4; ++r) {
      const float c = fmaf(v[r], c_reg[r], vi[r] * vg[r]);
      c_reg[r] = c;
      hv[r] = vo[r] * fast_tanh(c);
    }
    // gather the 4 contiguous columns (j0w..j0w+3) onto lane n==0
    float h1[4], h2[4], h3[4];
#pragma unroll
    for (int r = 0; r < 4; ++r) {
      h1[r] = __shfl(hv[r], (lane + 1) & 63, 64);
      h2[r] = __shfl(hv[r], (lane + 2) & 63, 64);
      h3[r] = __shfl(hv[r], (lane + 3) & 63, 64);
    }
    // packed 8B fp16 h-store, sc1 write-through (must precede arrival)
    if (n == 0) {
#pragma unroll
      for (int r = 0; r < 4; ++r) {
        const int b = brow0 + q * 4 + r;
        union {
          _Float16 h[4];
          unsigned long long u;
        } pk;
        pk.h[0] = (_Float16)hv[r];
        pk.h[1] = (_Float16)h1[r];
        pk.h[2] = (_Float16)h2[r];
        pk.h[3] = (_Float16)h3[r];
        store_sc1_u64(hb_next + (size_t)b * H + j0w, pk.u);
      }
    }

    // ---- fallback: stage x[t+1] rows of OWN group into next buffer ----
    if (!PRE && t + 1 < T_STEPS && tid < 16) {
      _Float16* xn = xbuf + (size_t)((t + 1) & 1) * B * IN;
      const int row = brow0 + (jgrp >> 2);         // 4 blocks per row
      const int off = (jgrp & 3) * 128 + tid * 8;  // quarter of 512
      const float* xs = x + (size_t)(t + 1) * B * IN + (size_t)row * IN + off;
      const float4 x0 = *(const float4*)xs;
      const float4 x1 = *(const float4*)(xs + 4);
      float vals[8] = {x0.x, x0.y, x0.z, x0.w, x1.x, x1.y, x1.z, x1.w};
#pragma unroll
      for (int i = 0; i < 4; ++i) {
        union {
          _Float16 h[2];
          unsigned u;
        } pk;
        pk.h[0] = (_Float16)vals[2 * i];
        pk.h[1] = (_Float16)vals[2 * i + 1];
        store_sc1_u32((unsigned*)(xn + (size_t)row * IN + off + 2 * i), pk.u);
      }
    }

    if (t + 1 < T_STEPS) {
      // drain this step's sc1 stores (compiler emits vmcnt(0) before
      // s_barrier), then release-publish this block's flag.
      __syncthreads();
      if (tid == 0) store_sc1_u32(flags + jgrp, (unsigned)(t + 1));
      // out-stores + next-step x GEMM hide under barrier propagation
      if (n == 0) {
#pragma unroll
        for (int r = 0; r < 4; ++r) {
          const int b = brow0 + q * 4 + r;
          const float4 o4 = make_float4(hv[r], h1[r], h2[r], h3[r]);
          *(float4*)(out + (size_t)t * B * H + (size_t)b * H + j0w) = o4;
        }
      }
      if (PRE) xpart(t + 1);
      // wave 0 scans the group's 64 flags (one u32 per lane, 4 lines);
      // waves 1-3 wait at a raw barrier (no vmcnt drain).
      if (wv == 0) {
        const unsigned tgt = (unsigned)(t + 1);
        for (;;) {
          const unsigned f = __hip_atomic_load(flags + lane, __ATOMIC_RELAXED,
                                               __HIP_MEMORY_SCOPE_AGENT);
          if (__all(f >= tgt)) break;
          __builtin_amdgcn_s_sleep(1);
        }
      }
      asm volatile("" ::: "memory");
      __builtin_amdgcn_s_barrier();
      asm volatile("" ::: "memory");
      if (!PRE) xpart(t + 1);  // xbuf sc1 loads are safe only post-poll
    } else {
      // final step: out row + hx + cx (no barrier needed)
      float c1[4], c2[4], c3[4];
#pragma unroll
      for (int r = 0; r < 4; ++r) {
        c1[r] = __shfl(c_reg[r], (lane + 1) & 63, 64);
        c2[r] = __shfl(c_reg[r], (lane + 2) & 63, 64);
        c3[r] = __shfl(c_reg[r], (lane + 3) & 63, 64);
      }
      if (n == 0) {
#pragma unroll
        for (int r = 0; r < 4; ++r) {
          const int b = brow0 + q * 4 + r;
          const float4 o4 = make_float4(hv[r], h1[r], h2[r], h3[r]);
          *(float4*)(out + (size_t)t * B * H + (size_t)b * H + j0w) = o4;
          *(float4*)(out + (size_t)T_STEPS * B * H + (size_t)b * H + j0w) =
              o4;  // hx
          const float4 c4 = make_float4(c_reg[r], c1[r], c2[r], c3[r]);
          *(float4*)(out + (size_t)T_STEPS * B * H + (size_t)B * H +
                     (size_t)b * H + j0w) = c4;  // cx
        }
      }
    }
  }
}

}  // namespace

extern "C" void kernel_launch(void* const* d_in, const int* in_sizes, int n_in,
                              void* d_out, int out_size, void* d_ws,
                              size_t ws_size, hipStream_t stream) {
  const float* x = (const float*)d_in[0];
  const float* Wf = (const float*)d_in[1];
  const float* bf = (const float*)d_in[2];
  const float* Wi = (const float*)d_in[3];
  const float* bi = (const float*)d_in[4];
  const float* Wg = (const float*)d_in[5];
  const float* bg = (const float*)d_in[6];
  const float* Wo = (const float*)d_in[7];
  const float* bo = (const float*)d_in[8];
  float* out = (float*)d_out;

  char* ws = (char*)d_ws;
  _Float16* hbuf = (_Float16*)(ws + HBUF_OFF);
  _Float16* xbuf = (_Float16*)(ws + XBUF_OFF);
  unsigned* bar = (unsigned*)(ws + BAR_OFF);
  _Float16* combx = (_Float16*)(ws + COMBX_OFF);

  const bool pre = ws_size >= NEED_PRE;

  if (pre) {
    const size_t n = (size_t)T_STEPS * B * IN;
    prep_pre<<<(unsigned)((n + 255) / 256), 256, 0, stream>>>(x, combx, hbuf,
                                                              bar);
    lstm_persist<true><<<NBLK, 256, 0, stream>>>(
        x, Wf, Wi, Wg, Wo, bf, bi, bg, bo, out, combx, xbuf, hbuf, bar);
  } else {
    prep_fb<<<(2 * B * H + 255) / 256, 256, 0, stream>>>(x, xbuf, hbuf, bar);
    lstm_persist<false><<<NBLK, 256, 0, stream>>>(
        x, Wf, Wi, Wg, Wo, bf, bi, bg, bo, out, combx, xbuf, hbuf, bar);
  }
}